// Round 26
// baseline (237.320 us; speedup 1.0000x reference)
//
#include <hip/hip_runtime.h>
#include <cstdint>
#include <cstddef>

#define BATCH 2
#define SEQ 2048
#define DMODEL 1024
#define NHEAD 16
#define DFF 4096
#define MTOT (BATCH * SEQ) /* 4096 */

typedef __bf16 bf16x8 __attribute__((ext_vector_type(8)));
typedef __bf16 bf16x4 __attribute__((ext_vector_type(4)));
typedef short s16x4 __attribute__((ext_vector_type(4)));
typedef float f32x4 __attribute__((ext_vector_type(4)));

#define S_BARRIER() __builtin_amdgcn_s_barrier()
#define SCHED_FENCE() __builtin_amdgcn_sched_barrier(0)
#define VMCNT8() asm volatile("s_waitcnt vmcnt(8)" ::: "memory")
#define VMCNT4() asm volatile("s_waitcnt vmcnt(4)" ::: "memory")
#define VMCNT0() asm volatile("s_waitcnt vmcnt(0)" ::: "memory")

// async global->LDS, 16B/lane; LDS dest = wave-uniform base + lane*16 (m104).
__device__ __forceinline__ void gload_lds16(const void* g, void* l) {
  __builtin_amdgcn_global_load_lds(
      (__attribute__((address_space(1))) void*)(uintptr_t)g,
      (__attribute__((address_space(3))) void*)(uint32_t)(uintptr_t)l,
      16, 0, 0);
}

// dtype-generic 4-wide loader for LN inputs
__device__ __forceinline__ float4 load4(const float* p, size_t idx) {
  return ((const float4*)p)[idx];
}
__device__ __forceinline__ float4 load4(const __bf16* p, size_t idx) {
  const bf16x4 v = ((const bf16x4*)p)[idx];
  return float4{(float)v[0], (float)v[1], (float)v[2], (float)v[3]};
}

// ---------------------------------------------------------------------------
// Fused prep (R24-verified): all weight transposes + bias concat + mask scale
// + x->bf16 in ONE dispatch. Block role by flat blockIdx range.
// ---------------------------------------------------------------------------
__global__ __launch_bounds__(256) void k_prep(
    const float* __restrict__ wq, const float* __restrict__ wk,
    const float* __restrict__ wv, const float* __restrict__ wo,
    const float* __restrict__ wff1, const float* __restrict__ wff2,
    __bf16* __restrict__ wqkvT, __bf16* __restrict__ woT,
    __bf16* __restrict__ wff1T, __bf16* __restrict__ wff2T,
    const float* __restrict__ bq, const float* __restrict__ bk,
    const float* __restrict__ bv, float* __restrict__ bqkv,
    const float* __restrict__ mask, float* __restrict__ mask2,
    const float* __restrict__ x, __bf16* __restrict__ xbf) {
  int f = blockIdx.x;
  if (f < 12) {  // concat3
    const int i = f * 256 + threadIdx.x;
    if (i < 3072)
      bqkv[i] = (i < 1024) ? bq[i] : (i < 2048) ? bk[i - 1024] : bv[i - 2048];
    return;
  }
  f -= 12;
  if (f < 16) {  // scale_mask
    const int i = f * 256 + threadIdx.x;
    if (i < BATCH * SEQ) mask2[i] = mask[i] * 1.44269504f;
    return;
  }
  f -= 16;
  if (f < 4096) {  // cvt_bf16
    const int i = (f * 256 + threadIdx.x) * 4;
    const float4 v = *(const float4*)(x + i);
    bf16x4 r;
    r[0] = (__bf16)v.x; r[1] = (__bf16)v.y; r[2] = (__bf16)v.z; r[3] = (__bf16)v.w;
    *(bf16x4*)(xbf + i) = r;
    return;
  }
  f -= 4096;
  const float* src;
  __bf16* dst;
  int Kd, Nd, n0, k0;
  if (f < 3072) {  // q/k/v
    const int zz = f / 1024, r = f % 1024;
    src = (zz == 0) ? wq : (zz == 1) ? wk : wv;
    dst = wqkvT + (size_t)zz * 1024 * 1024;
    Kd = 1024; Nd = 1024; n0 = (r & 31) * 32; k0 = (r >> 5) * 32;
  } else if (f < 4096) {  // wo
    const int r = f - 3072;
    src = wo; dst = woT;
    Kd = 1024; Nd = 1024; n0 = (r & 31) * 32; k0 = (r >> 5) * 32;
  } else if (f < 8192) {  // ff1
    const int r = f - 4096;
    src = wff1; dst = wff1T;
    Kd = 1024; Nd = 4096; n0 = (r & 127) * 32; k0 = (r >> 7) * 32;
  } else {  // ff2
    const int r = f - 8192;
    src = wff2; dst = wff2T;
    Kd = 4096; Nd = 1024; n0 = (r & 31) * 32; k0 = (r >> 5) * 32;
  }
  __shared__ float t[32][33];
  const int tx = threadIdx.x & 31, ty = threadIdx.x >> 5;
#pragma unroll
  for (int i = ty; i < 32; i += 8) t[i][tx] = src[(size_t)(k0 + i) * Nd + n0 + tx];
  __syncthreads();
#pragma unroll
  for (int i = ty; i < 32; i += 8)
    dst[(size_t)(n0 + i) * Kd + k0 + tx] = (__bf16)t[tx][i];
}

// ---------------------------------------------------------------------------
// Vectorized V transpose (R25-verified): 64x64 tiles, bf16x8 both directions.
// ---------------------------------------------------------------------------
__global__ __launch_bounds__(256) void k_transpose_v(
    const __bf16* __restrict__ qkvb, __bf16* __restrict__ vT) {
  __shared__ __bf16 t[64][72];  // +8 pad
  const int s0 = blockIdx.x * 64, c0 = blockIdx.y * 64, b = blockIdx.z;
  const int vc = threadIdx.x & 7;
  const int rw = threadIdx.x >> 3;
#pragma unroll
  for (int half = 0; half < 2; ++half) {
    const int row = rw + half * 32;
    *(bf16x8*)&t[row][vc * 8] =
        *(const bf16x8*)&qkvb[(size_t)(b * SEQ + s0 + row) * 3072 + 2048 + c0 + vc * 8];
  }
  __syncthreads();
#pragma unroll
  for (int half = 0; half < 2; ++half) {
    const int c = rw + half * 32;
    bf16x8 v;
#pragma unroll
    for (int i = 0; i < 8; ++i) v[i] = t[vc * 8 + i][c];
    *(bf16x8*)&vT[((size_t)b * 1024 + c0 + c) * SEQ + s0 + vc * 8] = v;
  }
}

// ---------------------------------------------------------------------------
// 256x256 deep-pipelined MFMA GEMM (T3+T4 counted-vmcnt, ALL-BUILTIN MFMAs).
// R16-verified. 512 thr = 8 waves (2M x 4N); wave owns 128x64.
// ---------------------------------------------------------------------------
template <bool RELU, typename OutT>
__global__ __launch_bounds__(512) void k_gemm256(
    const __bf16* __restrict__ A, const __bf16* __restrict__ BT,
    const float* __restrict__ bias, OutT* __restrict__ C,
    int M, int N, int K) {
  __shared__ __align__(16) __bf16 sA[4 * 8192];
  __shared__ __align__(16) __bf16 sB[4 * 8192];
  const int tid = threadIdx.x, lane = tid & 63, wv = tid >> 6;
  const int wm = wv >> 2, wn = wv & 3;
  const int lrow = lane & 15, hi = lane >> 4;
  const int nwg = gridDim.x * gridDim.y;
  const int flat = blockIdx.y * gridDim.x + blockIdx.x;
  const int cpx = nwg >> 3;
  const int swzb = (flat & 7) * cpx + (flat >> 3);
  const int m0 = (swzb / gridDim.x) * 256;
  const int n0 = (swzb % gridDim.x) * 256;
  const int NT = K >> 6;

  const int lsub = lane >> 2;
  const int gg = (lane & 3) ^ ((lane >> 3) & 3);
  const int gr = hi ^ ((lrow >> 1) & 3);

  f32x4 acc[8][4];
#pragma unroll
  for (int r = 0; r < 8; ++r)
#pragma unroll
    for (int c = 0; c < 4; ++c) acc[r][c] = f32x4{0.f, 0.f, 0.f, 0.f};

  auto stage = [&](int p) {
    const int tile = p >> 1;
    const int slot = (((tile & 1) * 2) + (p & 1)) * 8192;
    const int kcol = tile * 64 + (p & 1) * 32 + gg * 8;
#pragma unroll
    for (int i = 0; i < 2; ++i) {
      const int c = wv * 2 + i;
      gload_lds16(A + (size_t)(m0 + c * 16 + lsub) * K + kcol, &sA[slot + c * 512]);
      gload_lds16(BT + (size_t)(n0 + c * 16 + lsub) * K + kcol, &sB[slot + c * 512]);
    }
  };

  auto compute = [&](int p) {
    const int slot = ((((p >> 1) & 1) * 2) + (p & 1)) * 8192;
    bf16x8 af[8], bfv[4];
#pragma unroll
    for (int r = 0; r < 8; ++r)
      af[r] = *(const bf16x8*)&sA[slot + (wm * 128 + r * 16 + lrow) * 32 + gr * 8];
#pragma unroll
    for (int c = 0; c < 4; ++c)
      bfv[c] = *(const bf16x8*)&sB[slot + (wn * 64 + c * 16 + lrow) * 32 + gr * 8];
    __builtin_amdgcn_s_setprio(1);
#pragma unroll
    for (int r = 0; r < 8; ++r)
#pragma unroll
      for (int c = 0; c < 4; ++c)
        acc[r][c] = __builtin_amdgcn_mfma_f32_16x16x32_bf16(af[r], bfv[c],
                                                            acc[r][c], 0, 0, 0);
    __builtin_amdgcn_s_setprio(0);
  };

  stage(0); stage(1); stage(2);
  int p = 0;
  for (; p < 2 * NT - 3; ++p) {
    VMCNT8(); S_BARRIER(); SCHED_FENCE();
    stage(p + 3);
    compute(p);
  }
  VMCNT8(); S_BARRIER(); SCHED_FENCE(); compute(p); ++p;
  VMCNT4(); S_BARRIER(); SCHED_FENCE(); compute(p); ++p;
  VMCNT0(); S_BARRIER(); SCHED_FENCE(); compute(p);

#pragma unroll
  for (int r = 0; r < 8; ++r) {
    const int row = m0 + wm * 128 + r * 16 + hi * 4;
#pragma unroll
    for (int c = 0; c < 4; ++c) {
      const int col = n0 + wn * 64 + c * 16 + lrow;
      const float bb = bias[col];
#pragma unroll
      for (int j = 0; j < 4; ++j) {
        float v = acc[r][c][j] + bb;
        if (RELU) v = fmaxf(v, 0.f);
        C[(size_t)(row + j) * N + col] = (OutT)v;
      }
    }
  }
}

// ---------------------------------------------------------------------------
// bf16 MFMA GEMM (R9-verified body + XCD swizzle) with single-dispatch
// split-K: blockIdx.z selects K-range, output buffer (z==0 -> C0 with bias,
// z==1 -> C1 with zero bias). BM=MF*32, BN=128, BK=64.
// ---------------------------------------------------------------------------
template <int MF, bool RELU, typename OutT>
__global__ __launch_bounds__(256) void k_gemm(
    const __bf16* __restrict__ A, const __bf16* __restrict__ BT,
    const float* __restrict__ bias, OutT* __restrict__ C0,
    OutT* __restrict__ C1, int M, int N, int lda, int KS) {
  __shared__ __bf16 sA[MF * 32 * 64];
  __shared__ __bf16 sB[128 * 64];
  const int tid = threadIdx.x, lane = tid & 63, wv = tid >> 6;
  const int wm = wv >> 1, wn = wv & 1;
  const int lrow = lane & 15, hi = lane >> 4;
  const int nwg = gridDim.x * gridDim.y;
  const int flat = blockIdx.y * gridDim.x + blockIdx.x;
  const int cpx = nwg >> 3;
  const int swzb = (flat & 7) * cpx + (flat >> 3);
  const int m0 = (swzb / gridDim.x) * (MF * 32);
  const int n0 = (swzb % gridDim.x) * 128;
  const int koff = blockIdx.z * KS;
  OutT* Cz = blockIdx.z ? C1 : C0;
  const int srow = lane >> 3;
  const int scolE = ((lane & 7) ^ srow) * 8;
  const int swz = (lrow & 7) << 4;

  f32x4 acc[MF][4];
#pragma unroll
  for (int r = 0; r < MF; ++r)
#pragma unroll
    for (int c = 0; c < 4; ++c) acc[r][c] = f32x4{0.f, 0.f, 0.f, 0.f};

  for (int k0 = 0; k0 < KS; k0 += 64) {
    __syncthreads();
#pragma unroll
    for (int rb = wv; rb < MF * 4; rb += 4) {
      const int row = rb * 8 + srow;
      gload_lds16(A + (size_t)(m0 + row) * lda + koff + k0 + scolE, &sA[rb * 512]);
    }
#pragma unroll
    for (int rb = wv; rb < 16; rb += 4) {
      const int row = rb * 8 + srow;
      gload_lds16(BT + (size_t)(n0 + row) * lda + koff + k0 + scolE, &sB[rb * 512]);
    }
    __syncthreads();
#pragma unroll
    for (int kc = 0; kc < 2; ++kc) {
      bf16x8 af[MF], bfr[4];
#pragma unroll
      for (int r = 0; r < MF; ++r) {
        const int row = wm * (MF * 16) + r * 16 + lrow;
        af[r] = *(const bf16x8*)((const char*)sA + row * 128 + ((kc * 64 + hi * 16) ^ swz));
      }
#pragma unroll
      for (int c = 0; c < 4; ++c) {
        const int row = wn * 64 + c * 16 + lrow;
        bfr[c] = *(const bf16x8*)((const char*)sB + row * 128 + ((kc * 64 + hi * 16) ^ swz));
      }
#pragma unroll
      for (int r = 0; r < MF; ++r)
#pragma unroll
        for (int c = 0; c < 4; ++c)
          acc[r][c] = __builtin_amdgcn_mfma_f32_16x16x32_bf16(af[r], bfr[c],
                                                              acc[r][c], 0, 0, 0);
    }
  }

#pragma unroll
  for (int r = 0; r < MF; ++r) {
    const int row = m0 + wm * (MF * 16) + r * 16 + hi * 4;
#pragma unroll
    for (int c = 0; c < 4; ++c) {
      const int col = n0 + wn * 64 + c * 16 + lrow;
      const float bb = (blockIdx.z == 0) ? bias[col] : 0.f;
#pragma unroll
      for (int j = 0; j < 4; ++j) {
        float v = acc[r][c][j] + bb;
        if (RELU) v = fmaxf(v, 0.f);
        Cz[(size_t)(row + j) * N + col] = (OutT)v;
      }
    }
  }
}

// ---------------------------------------------------------------------------
// Flash attention — R23 compute body (QBLK=128 x KVBLK=128, 8 waves, exp2 +
// defer-max softmax, XCD-clustered grid), staging switched to SINGLE-BUFFER
// with the R2/R9/R13-verified protocol (sync; issue gload_lds; sync;
// compute). LDS 64KB -> 32KB: 4 blocks/CU co-resident = 32 waves/CU (was 16)
// — R15 showed dbuf ~ flat vs single-buffer, so spend the LDS on residency;
// co-resident blocks cover each other's stage drains (m114).
// ---------------------------------------------------------------------------
__global__ __launch_bounds__(512) void k_attn(
    const __bf16* __restrict__ qkv, const __bf16* __restrict__ vT,
    const float* __restrict__ mask2, __bf16* __restrict__ out) {
  const int nwg = gridDim.x * gridDim.y * gridDim.z;          // 512
  const int flat = (blockIdx.z * gridDim.y + blockIdx.y) * gridDim.x + blockIdx.x;
  const int cpx = nwg >> 3;                                   // 64
  const int swzb = (flat & 7) * cpx + (flat >> 3);
  const int qb = swzb & (gridDim.x - 1);
  const int h = (swzb >> 4) & 15;
  const int b = swzb >> 8;
  const int tid = threadIdx.x, lane = tid & 63, wv = tid >> 6;
  const int lrow = lane & 15, hi = lane >> 4;

  __shared__ __bf16 sK[128 * 64];   // [key][d], swizzled (16KB)
  __shared__ __bf16 sV0[64 * 64];   // [d][key 0..64)  (8KB)
  __shared__ __bf16 sV1[64 * 64];   // [d][key 64..128) (8KB)

  const size_t base = (size_t)b * SEQ * 3072;
  const __bf16* Qb = qkv + base + h * 64;
  const __bf16* Kb = qkv + base + 1024 + h * 64;
  const __bf16* vTb = vT + ((size_t)b * 1024 + h * 64) * SEQ;
  const float* maskb = mask2 + (size_t)b * SEQ;

  const int q0 = qb * 128 + wv * 16;
  const bf16x8 qf0 = *(const bf16x8*)&Qb[(size_t)(q0 + lrow) * 3072 + hi * 8];
  const bf16x8 qf1 = *(const bf16x8*)&Qb[(size_t)(q0 + lrow) * 3072 + 32 + hi * 8];

  float m_r = -3e38f, l_r = 0.f;
  f32x4 o[4];
#pragma unroll
  for (int d = 0; d < 4; ++d) o[d] = f32x4{0.f, 0.f, 0.f, 0.f};

  const int srow = lane >> 3;
  const int scolE = ((lane & 7) ^ srow) * 8;
  const int swz = (lrow & 7) << 4;

  const int NT = SEQ / 128;
  for (int t = 0; t < NT; ++t) {
    const int k0s = t * 128;
    __syncthreads();  // prior iteration's LDS reads complete (WAR guard)
#pragma unroll
    for (int r = 0; r < 2; ++r) {  // K: 16 chunks over 8 waves
      const int rb = wv + r * 8;
      const int row = rb * 8 + srow;
      gload_lds16(Kb + (size_t)(k0s + row) * 3072 + scolE, &sK[rb * 512]);
    }
    const int vrow = wv * 8 + srow;  // V: chunk wv of each 64-key half
    gload_lds16(vTb + (size_t)vrow * SEQ + k0s + scolE, &sV0[wv * 512]);
    gload_lds16(vTb + (size_t)vrow * SEQ + k0s + 64 + scolE, &sV1[wv * 512]);
    __syncthreads();  // vmcnt drain: staged data visible block-wide
    const int k0 = t * 128;

    f32x4 st[8];
#pragma unroll
    for (int t4 = 0; t4 < 8; ++t4) {
      const char* rp = (const char*)sK + (t4 * 16 + lrow) * 128;
      const bf16x8 ka = *(const bf16x8*)(rp + ((hi * 16) ^ swz));
      const bf16x8 kb = *(const bf16x8*)(rp + ((64 + hi * 16) ^ swz));
      f32x4 a = f32x4{0.f, 0.f, 0.f, 0.f};
      a = __builtin_amdgcn_mfma_f32_16x16x32_bf16(ka, qf0, a, 0, 0, 0);
      a = __builtin_amdgcn_mfma_f32_16x16x32_bf16(kb, qf1, a, 0, 0, 0);
      st[t4] = a;
    }

    float pm = -3e38f;
#pragma unroll
    for (int t4 = 0; t4 < 8; ++t4) {
      const f32x4 mk = *(const f32x4*)&maskb[k0 + t4 * 16 + hi * 4];
#pragma unroll
      for (int j = 0; j < 4; ++j) {
        st[t4][j] = st[t4][j] * 0.18033688f + mk[j];
        pm = fmaxf(pm, st[t4][j]);
      }
    }
    pm = fmaxf(pm, __shfl_xor(pm, 16));
    pm = fmaxf(pm, __shfl_xor(pm, 32));

    if (__any(pm > m_r + 11.5f)) {
      const float mn = fmaxf(m_r, pm);
      const float so = __builtin_amdgcn_exp2f(m_r - mn);
      m_r = mn;
      l_r *= so;
      float so_o[4];
#pragma unroll
      for (int jj = 0; jj < 4; ++jj) so_o[jj] = __shfl(so, hi * 4 + jj);
#pragma unroll
      for (int d = 0; d < 4; ++d)
#pragma unroll
        for (int jj = 0; jj < 4; ++jj) o[d][jj] *= so_o[jj];
    }

    float rs = 0.f;
#pragma unroll
    for (int t4 = 0; t4 < 8; ++t4)
#pragma unroll
      for (int j = 0; j < 4; ++j) {
        st[t4][j] = __builtin_amdgcn_exp2f(st[t4][j] - m_r);
        rs += st[t4][j];
      }
    rs += __shfl_xor(rs, 16);
    rs += __shfl_xor(rs, 32);
    l_r += rs;

    s16x4 pa[8];
#pragma unroll
    for (int t4 = 0; t4 < 8; ++t4)
#pragma unroll
      for (int j = 0; j < 4; ++j) {
        const __bf16 pb = (__bf16)st[t4][j];
        pa[t4][j] = __builtin_bit_cast(short, pb);
      }

#pragma unroll
    for (int d = 0; d < 4; ++d) {
      const char* rp0 = (const char*)sV0 + (d * 16 + lrow) * 128;
      const char* rp1 = (const char*)sV1 + (d * 16 + lrow) * 128;
#pragma unroll
      for (int t4 = 0; t4 < 4; ++t4) {
        const s16x4 vb0 = *(const s16x4*)(rp0 + ((t4 * 32 + hi * 8) ^ swz));
        o[d] = __builtin_amdgcn_mfma_f32_16x16x16bf16_1k(pa[t4], vb0, o[d], 0, 0, 0);
        const s16x4 vb1 = *(const s16x4*)(rp1 + ((t4 * 32 + hi * 8) ^ swz));
        o[d] = __builtin_amdgcn_mfma_f32_16x16x16bf16_1k(pa[4 + t4], vb1, o[d], 0, 0, 0);
      }
    }
  }

  __syncthreads();
  float linv[4];
#pragma unroll
  for (int jj = 0; jj < 4; ++jj) linv[jj] = 1.0f / __shfl(l_r, hi * 4 + jj);
#pragma unroll
  for (int d = 0; d < 4; ++d)
#pragma unroll
    for (int jj = 0; jj < 4; ++jj)
      out[((size_t)b * SEQ + q0 + hi * 4 + jj) * DMODEL + h * 64 + d * 16 + lrow] =
          (__bf16)(o[d][jj] * linv[jj]);
}

// ---------------------------------------------------------------------------
// out = LayerNorm(x + y [+ y2]) * g + beta. Inputs dtype-templated (f32 or
// bf16); y/y2 nullable; f32 out (of) and bf16 out (ob) each optional.
// ---------------------------------------------------------------------------
template <typename TX, typename TY, typename TY2>
__global__ __launch_bounds__(256) void k_add_ln(
    const TX* __restrict__ x, const TY* __restrict__ y,
    const TY2* __restrict__ y2, const float* __restrict__ g,
    const float* __restrict__ be, float* __restrict__ of,
    __bf16* __restrict__ ob) {
  const int row = blockIdx.x, tid = threadIdx.x;
  const size_t idx = (size_t)row * 256 + tid;
  const float4 a = load4(x, idx);
  float4 b = {0.f, 0.f, 0.f, 0.f};
  if (y) b = load4(y, idx);
  float4 c = {0.f, 0.f, 0.f, 0.f};
  if (y2) c = load4(y2, idx);
  const float v0 = a.x + b.x + c.x, v1 = a.y + b.y + c.y;
  const float v2 = a.z + b.z + c.z, v3 = a.w + b.w + c.w;
  float s = v0 + v1 + v2 + v3;
  float s2 = v0 * v0 + v1 * v1 + v2 * v2 + v3 * v3;
#pragma unroll
  for (int off = 32; off > 0; off >>= 1) {
    s += __shfl_xor(s, off);
    s2 += __shfl_xor(s2, off);
  }
  __shared__ float red[2][4];
  const int wv = tid >> 6, lane = tid & 63;
  if (lane == 0) { red[0][wv] = s; red[1][wv] = s2; }
  __syncthreads();
  s = red[0][0] + red[0][1] + red[0][2] + red[0][3];
  s2 = red[1][0] + red[1][1] + red[1][2] + red[1][3];
  const float mean = s * (1.0f / 1024.0f);
  const float var = s2 * (1.0f / 1024.0f) - mean * mean;
  const float rstd = rsqrtf(var + 1e-5f);
  const float4 gg = ((const float4*)g)[tid];
  const float4 bt = ((const float4*)be)[tid];
  float4 r;
  r.x = (v0 - mean) * rstd * gg.x + bt.x;
  r.y = (v1 - mean) * rstd * gg.y + bt.y;
  r.z = (v2 - mean) * rstd * gg.z + bt.z;
  r.w = (v3 - mean) * rstd * gg.w + bt.w;
  if (of) ((float4*)(of + (size_t)row * 1024))[tid] = r;
  if (ob) {
    bf16x4 rb;
    rb[0] = (__bf16)r.x; rb[1] = (__bf16)r.y; rb[2] = (__bf16)r.z; rb[3] = (__bf16)r.w;
    *(bf16x4*)(ob + (size_t)row * 1024 + tid * 4) = rb;
  }
}

// ---------------------------------------------------------------------------
extern "C" void kernel_launch(void* const* d_in, const int* in_sizes, int n_in,
                              void* d_out, int out_size, void* d_ws, size_t ws_size,
                              hipStream_t stream) {
  const float* x = (const float*)d_in[0];
  const float* src_mask = (const float*)d_in[1];
  const float* w_q = (const float*)d_in[2];
  const float* b_q = (const float*)d_in[3];
  const float* w_k = (const float*)d_in[4];
  const float* b_k = (const float*)d_in[5];
  const float* w_v = (const float*)d_in[6];
  const float* b_v = (const float*)d_in[7];
  const float* w_o = (const float*)d_in[8];
  const float* b_o = (const float*)d_in[9];
  const float* w_ff1 = (const float*)d_in[10];
  const float* b_ff1 = (const float*)d_in[11];
  const float* w_ff2 = (const float*)d_in[12];
  const float* b_ff2 = (const float*)d_in[13];
  const float* ln1_g = (const float*)d_in[14];
  const float* ln1_b = (const float*)d_in[15];
  const float* ln2_g = (const float*)d_in[16];
  const float* ln2_b = (const float*)d_in[17];

  char* ws = (char*)d_ws;
  constexpr size_t O_WQKVT = 0;
  constexpr size_t O_WOT = O_WQKVT + 3072ull * 1024 * 2;
  constexpr size_t O_WFF1T = O_WOT + 1024ull * 1024 * 2;
  constexpr size_t O_WFF2T = O_WFF1T + 4096ull * 1024 * 2;
  constexpr size_t O_BQKV = O_WFF2T + 4096ull * 1024 * 2;
  constexpr size_t O_XBF = O_BQKV + 3072ull * 4;
  constexpr size_t O_QKV = O_XBF + 4096ull * 1024 * 2;
  constexpr size_t O_ATTN = O_QKV + 4096ull * 3072 * 2;
  constexpr size_t O_PROJ = O_ATTN + 4096ull * 1024 * 2;   // region reused 3x
  constexpr size_t O_H1F = O_PROJ + 4096ull * 1024 * 4;
  constexpr size_t O_H1B = O_H1F + 4096ull * 1024 * 4;
  constexpr size_t O_MASK2 = O_H1B + 4096ull * 1024 * 2;   // 16KB
  constexpr size_t O_VT = O_PROJ;    // vT (8MB): dead once proj written
  constexpr size_t O_FF = O_QKV;     // ffb 32MB spans QKV+ATTN
  constexpr size_t O_PROJB = O_PROJ; // proj bf16 8MB (after vT dead)
  constexpr size_t O_FF2A = O_PROJ;  // ff2a bf16 8MB (projb dead after ln1)
  constexpr size_t O_FF2B = 0;       // ff2b bf16 8MB over dead wqkvT+woT

  __bf16* wqkvT = (__bf16*)(ws + O_WQKVT);
  __bf16* woT = (__bf16*)(ws + O_WOT);
  __bf16* wff1T = (__bf16*)(ws + O_WFF1T);
  __bf16* wff2T = (__bf16*)(ws + O_WFF2T);
  float* bqkv = (float*)(ws + O_BQKV);
  __bf16* xbf = (__bf16*)(ws + O_XBF);
  __bf16* qkvb = (__bf16*)(ws + O_QKV);
  __bf16* attnb = (__bf16*)(ws + O_ATTN);
  __bf16* projb = (__bf16*)(ws + O_PROJB);
  __bf16* h1b = (__bf16*)(ws + O_H1B);
  float* mask2 = (float*)(ws + O_MASK2);
  __bf16* vT = (__bf16*)(ws + O_VT);
  __bf16* ffb = (__bf16*)(ws + O_FF);
  __bf16* ff2a = (__bf16*)(ws + O_FF2A);
  __bf16* ff2b = (__bf16*)(ws + O_FF2B);

  // fused prep: all transposes + concat + mask scale + x->bf16, ONE dispatch
  k_prep<<<16412, 256, 0, stream>>>(w_q, w_k, w_v, w_o, w_ff1, w_ff2,
                                    wqkvT, woT, wff1T, wff2T,
                                    b_q, b_k, b_v, bqkv,
                                    src_mask, mask2, x, xbf);

  // fused QKV projection (256^2 counted-vmcnt pipeline)
  k_gemm256<false, __bf16><<<dim3(12, 16), 512, 0, stream>>>(xbf, wqkvT, bqkv, qkvb,
                                                             MTOT, 3072, 1024);
  // V transpose (vectorized 64x64 tiles)
  k_transpose_v<<<dim3(32, 16, 2), 256, 0, stream>>>(qkvb, vT);
  // attention (QBLK=128 x KVBLK=128, single-buffer, 4 blocks/CU)
  k_attn<<<dim3(SEQ / 128, NHEAD, BATCH), 512, 0, stream>>>(qkvb, vT, mask2, attnb);
  // output projection -> bf16
  k_gemm<2, false, __bf16><<<dim3(8, 64, 1), 256, 0, stream>>>(
      attnb, woT, b_o, projb, nullptr, MTOT, 1024, 1024, 1024);
  // ln1: h1 = LN(x + proj) -> bf16 only
  k_add_ln<float, __bf16, float><<<4096, 256, 0, stream>>>(
      x, projb, (const float*)nullptr, ln1_g, ln1_b, nullptr, h1b);
  // ff1 + relu (256^2 counted-vmcnt pipeline)
  k_gemm256<true, __bf16><<<dim3(16, 16), 512, 0, stream>>>(h1b, wff1T, b_ff1, ffb,
                                                            MTOT, DFF, 1024);
  // ff2 split-K x2 in ONE dispatch, bf16 partials
  k_gemm<2, false, __bf16><<<dim3(8, 64, 2), 256, 0, stream>>>(
      ffb, wff2T, b_ff2, ff2a, ff2b, MTOT, 1024, DFF, 2048);
  // ln2 -> d_out: ff2a + h1b + ff2b (all bf16 in, f32 out)
  k_add_ln<__bf16, __bf16, __bf16><<<4096, 256, 0, stream>>>(
      ff2a, h1b, ff2b, ln2_g, ln2_b, (float*)d_out, nullptr);
}

// Round 27
// 234.431 us; speedup vs baseline: 1.0123x; 1.0123x over previous
//
#include <hip/hip_runtime.h>
#include <cstdint>
#include <cstddef>

#define BATCH 2
#define SEQ 2048
#define DMODEL 1024
#define NHEAD 16
#define DFF 4096
#define MTOT (BATCH * SEQ) /* 4096 */

typedef __bf16 bf16x8 __attribute__((ext_vector_type(8)));
typedef __bf16 bf16x4 __attribute__((ext_vector_type(4)));
typedef short s16x4 __attribute__((ext_vector_type(4)));
typedef float f32x4 __attribute__((ext_vector_type(4)));

#define S_BARRIER() __builtin_amdgcn_s_barrier()
#define SCHED_FENCE() __builtin_amdgcn_sched_barrier(0)
#define VMCNT8() asm volatile("s_waitcnt vmcnt(8)" ::: "memory")
#define VMCNT4() asm volatile("s_waitcnt vmcnt(4)" ::: "memory")
#define VMCNT0() asm volatile("s_waitcnt vmcnt(0)" ::: "memory")

// async global->LDS, 16B/lane; LDS dest = wave-uniform base + lane*16 (m104).
__device__ __forceinline__ void gload_lds16(const void* g, void* l) {
  __builtin_amdgcn_global_load_lds(
      (__attribute__((address_space(1))) void*)(uintptr_t)g,
      (__attribute__((address_space(3))) void*)(uint32_t)(uintptr_t)l,
      16, 0, 0);
}

// dtype-generic 4-wide loader for LN inputs
__device__ __forceinline__ float4 load4(const float* p, size_t idx) {
  return ((const float4*)p)[idx];
}
__device__ __forceinline__ float4 load4(const __bf16* p, size_t idx) {
  const bf16x4 v = ((const bf16x4*)p)[idx];
  return float4{(float)v[0], (float)v[1], (float)v[2], (float)v[3]};
}

// ---------------------------------------------------------------------------
// Fused prep (R24-verified): all weight transposes + bias concat + mask scale
// + x->bf16 in ONE dispatch. Block role by flat blockIdx range.
// ---------------------------------------------------------------------------
__global__ __launch_bounds__(256) void k_prep(
    const float* __restrict__ wq, const float* __restrict__ wk,
    const float* __restrict__ wv, const float* __restrict__ wo,
    const float* __restrict__ wff1, const float* __restrict__ wff2,
    __bf16* __restrict__ wqkvT, __bf16* __restrict__ woT,
    __bf16* __restrict__ wff1T, __bf16* __restrict__ wff2T,
    const float* __restrict__ bq, const float* __restrict__ bk,
    const float* __restrict__ bv, float* __restrict__ bqkv,
    const float* __restrict__ mask, float* __restrict__ mask2,
    const float* __restrict__ x, __bf16* __restrict__ xbf) {
  int f = blockIdx.x;
  if (f < 12) {  // concat3
    const int i = f * 256 + threadIdx.x;
    if (i < 3072)
      bqkv[i] = (i < 1024) ? bq[i] : (i < 2048) ? bk[i - 1024] : bv[i - 2048];
    return;
  }
  f -= 12;
  if (f < 16) {  // scale_mask
    const int i = f * 256 + threadIdx.x;
    if (i < BATCH * SEQ) mask2[i] = mask[i] * 1.44269504f;
    return;
  }
  f -= 16;
  if (f < 4096) {  // cvt_bf16
    const int i = (f * 256 + threadIdx.x) * 4;
    const float4 v = *(const float4*)(x + i);
    bf16x4 r;
    r[0] = (__bf16)v.x; r[1] = (__bf16)v.y; r[2] = (__bf16)v.z; r[3] = (__bf16)v.w;
    *(bf16x4*)(xbf + i) = r;
    return;
  }
  f -= 4096;
  const float* src;
  __bf16* dst;
  int Kd, Nd, n0, k0;
  if (f < 3072) {  // q/k/v
    const int zz = f / 1024, r = f % 1024;
    src = (zz == 0) ? wq : (zz == 1) ? wk : wv;
    dst = wqkvT + (size_t)zz * 1024 * 1024;
    Kd = 1024; Nd = 1024; n0 = (r & 31) * 32; k0 = (r >> 5) * 32;
  } else if (f < 4096) {  // wo
    const int r = f - 3072;
    src = wo; dst = woT;
    Kd = 1024; Nd = 1024; n0 = (r & 31) * 32; k0 = (r >> 5) * 32;
  } else if (f < 8192) {  // ff1
    const int r = f - 4096;
    src = wff1; dst = wff1T;
    Kd = 1024; Nd = 4096; n0 = (r & 127) * 32; k0 = (r >> 7) * 32;
  } else {  // ff2
    const int r = f - 8192;
    src = wff2; dst = wff2T;
    Kd = 4096; Nd = 1024; n0 = (r & 31) * 32; k0 = (r >> 5) * 32;
  }
  __shared__ float t[32][33];
  const int tx = threadIdx.x & 31, ty = threadIdx.x >> 5;
#pragma unroll
  for (int i = ty; i < 32; i += 8) t[i][tx] = src[(size_t)(k0 + i) * Nd + n0 + tx];
  __syncthreads();
#pragma unroll
  for (int i = ty; i < 32; i += 8)
    dst[(size_t)(n0 + i) * Kd + k0 + tx] = (__bf16)t[tx][i];
}

// ---------------------------------------------------------------------------
// Vectorized V transpose (R25-verified): 64x64 tiles, bf16x8 both directions.
// ---------------------------------------------------------------------------
__global__ __launch_bounds__(256) void k_transpose_v(
    const __bf16* __restrict__ qkvb, __bf16* __restrict__ vT) {
  __shared__ __bf16 t[64][72];  // +8 pad
  const int s0 = blockIdx.x * 64, c0 = blockIdx.y * 64, b = blockIdx.z;
  const int vc = threadIdx.x & 7;
  const int rw = threadIdx.x >> 3;
#pragma unroll
  for (int half = 0; half < 2; ++half) {
    const int row = rw + half * 32;
    *(bf16x8*)&t[row][vc * 8] =
        *(const bf16x8*)&qkvb[(size_t)(b * SEQ + s0 + row) * 3072 + 2048 + c0 + vc * 8];
  }
  __syncthreads();
#pragma unroll
  for (int half = 0; half < 2; ++half) {
    const int c = rw + half * 32;
    bf16x8 v;
#pragma unroll
    for (int i = 0; i < 8; ++i) v[i] = t[vc * 8 + i][c];
    *(bf16x8*)&vT[((size_t)b * 1024 + c0 + c) * SEQ + s0 + vc * 8] = v;
  }
}

// ---------------------------------------------------------------------------
// 256x256 deep-pipelined MFMA GEMM (T3+T4 counted-vmcnt, ALL-BUILTIN MFMAs).
// R16-verified. 512 thr = 8 waves (2M x 4N); wave owns 128x64.
// ---------------------------------------------------------------------------
template <bool RELU, typename OutT>
__global__ __launch_bounds__(512) void k_gemm256(
    const __bf16* __restrict__ A, const __bf16* __restrict__ BT,
    const float* __restrict__ bias, OutT* __restrict__ C,
    int M, int N, int K) {
  __shared__ __align__(16) __bf16 sA[4 * 8192];
  __shared__ __align__(16) __bf16 sB[4 * 8192];
  const int tid = threadIdx.x, lane = tid & 63, wv = tid >> 6;
  const int wm = wv >> 2, wn = wv & 3;
  const int lrow = lane & 15, hi = lane >> 4;
  const int nwg = gridDim.x * gridDim.y;
  const int flat = blockIdx.y * gridDim.x + blockIdx.x;
  const int cpx = nwg >> 3;
  const int swzb = (flat & 7) * cpx + (flat >> 3);
  const int m0 = (swzb / gridDim.x) * 256;
  const int n0 = (swzb % gridDim.x) * 256;
  const int NT = K >> 6;

  const int lsub = lane >> 2;
  const int gg = (lane & 3) ^ ((lane >> 3) & 3);
  const int gr = hi ^ ((lrow >> 1) & 3);

  f32x4 acc[8][4];
#pragma unroll
  for (int r = 0; r < 8; ++r)
#pragma unroll
    for (int c = 0; c < 4; ++c) acc[r][c] = f32x4{0.f, 0.f, 0.f, 0.f};

  auto stage = [&](int p) {
    const int tile = p >> 1;
    const int slot = (((tile & 1) * 2) + (p & 1)) * 8192;
    const int kcol = tile * 64 + (p & 1) * 32 + gg * 8;
#pragma unroll
    for (int i = 0; i < 2; ++i) {
      const int c = wv * 2 + i;
      gload_lds16(A + (size_t)(m0 + c * 16 + lsub) * K + kcol, &sA[slot + c * 512]);
      gload_lds16(BT + (size_t)(n0 + c * 16 + lsub) * K + kcol, &sB[slot + c * 512]);
    }
  };

  auto compute = [&](int p) {
    const int slot = ((((p >> 1) & 1) * 2) + (p & 1)) * 8192;
    bf16x8 af[8], bfv[4];
#pragma unroll
    for (int r = 0; r < 8; ++r)
      af[r] = *(const bf16x8*)&sA[slot + (wm * 128 + r * 16 + lrow) * 32 + gr * 8];
#pragma unroll
    for (int c = 0; c < 4; ++c)
      bfv[c] = *(const bf16x8*)&sB[slot + (wn * 64 + c * 16 + lrow) * 32 + gr * 8];
    __builtin_amdgcn_s_setprio(1);
#pragma unroll
    for (int r = 0; r < 8; ++r)
#pragma unroll
      for (int c = 0; c < 4; ++c)
        acc[r][c] = __builtin_amdgcn_mfma_f32_16x16x32_bf16(af[r], bfv[c],
                                                            acc[r][c], 0, 0, 0);
    __builtin_amdgcn_s_setprio(0);
  };

  stage(0); stage(1); stage(2);
  int p = 0;
  for (; p < 2 * NT - 3; ++p) {
    VMCNT8(); S_BARRIER(); SCHED_FENCE();
    stage(p + 3);
    compute(p);
  }
  VMCNT8(); S_BARRIER(); SCHED_FENCE(); compute(p); ++p;
  VMCNT4(); S_BARRIER(); SCHED_FENCE(); compute(p); ++p;
  VMCNT0(); S_BARRIER(); SCHED_FENCE(); compute(p);

#pragma unroll
  for (int r = 0; r < 8; ++r) {
    const int row = m0 + wm * 128 + r * 16 + hi * 4;
#pragma unroll
    for (int c = 0; c < 4; ++c) {
      const int col = n0 + wn * 64 + c * 16 + lrow;
      const float bb = bias[col];
#pragma unroll
      for (int j = 0; j < 4; ++j) {
        float v = acc[r][c][j] + bb;
        if (RELU) v = fmaxf(v, 0.f);
        C[(size_t)(row + j) * N + col] = (OutT)v;
      }
    }
  }
}

// ---------------------------------------------------------------------------
// bf16 MFMA GEMM (R9-verified body + XCD swizzle) with single-dispatch
// split-K: blockIdx.z selects K-range, output buffer (z==0 -> C0 with bias,
// z==1 -> C1 with zero bias). BM=MF*32, BN=128, BK=64.
// ---------------------------------------------------------------------------
template <int MF, bool RELU, typename OutT>
__global__ __launch_bounds__(256) void k_gemm(
    const __bf16* __restrict__ A, const __bf16* __restrict__ BT,
    const float* __restrict__ bias, OutT* __restrict__ C0,
    OutT* __restrict__ C1, int M, int N, int lda, int KS) {
  __shared__ __bf16 sA[MF * 32 * 64];
  __shared__ __bf16 sB[128 * 64];
  const int tid = threadIdx.x, lane = tid & 63, wv = tid >> 6;
  const int wm = wv >> 1, wn = wv & 1;
  const int lrow = lane & 15, hi = lane >> 4;
  const int nwg = gridDim.x * gridDim.y;
  const int flat = blockIdx.y * gridDim.x + blockIdx.x;
  const int cpx = nwg >> 3;
  const int swzb = (flat & 7) * cpx + (flat >> 3);
  const int m0 = (swzb / gridDim.x) * (MF * 32);
  const int n0 = (swzb % gridDim.x) * 128;
  const int koff = blockIdx.z * KS;
  OutT* Cz = blockIdx.z ? C1 : C0;
  const int srow = lane >> 3;
  const int scolE = ((lane & 7) ^ srow) * 8;
  const int swz = (lrow & 7) << 4;

  f32x4 acc[MF][4];
#pragma unroll
  for (int r = 0; r < MF; ++r)
#pragma unroll
    for (int c = 0; c < 4; ++c) acc[r][c] = f32x4{0.f, 0.f, 0.f, 0.f};

  for (int k0 = 0; k0 < KS; k0 += 64) {
    __syncthreads();
#pragma unroll
    for (int rb = wv; rb < MF * 4; rb += 4) {
      const int row = rb * 8 + srow;
      gload_lds16(A + (size_t)(m0 + row) * lda + koff + k0 + scolE, &sA[rb * 512]);
    }
#pragma unroll
    for (int rb = wv; rb < 16; rb += 4) {
      const int row = rb * 8 + srow;
      gload_lds16(BT + (size_t)(n0 + row) * lda + koff + k0 + scolE, &sB[rb * 512]);
    }
    __syncthreads();
#pragma unroll
    for (int kc = 0; kc < 2; ++kc) {
      bf16x8 af[MF], bfr[4];
#pragma unroll
      for (int r = 0; r < MF; ++r) {
        const int row = wm * (MF * 16) + r * 16 + lrow;
        af[r] = *(const bf16x8*)((const char*)sA + row * 128 + ((kc * 64 + hi * 16) ^ swz));
      }
#pragma unroll
      for (int c = 0; c < 4; ++c) {
        const int row = wn * 64 + c * 16 + lrow;
        bfr[c] = *(const bf16x8*)((const char*)sB + row * 128 + ((kc * 64 + hi * 16) ^ swz));
      }
#pragma unroll
      for (int r = 0; r < MF; ++r)
#pragma unroll
        for (int c = 0; c < 4; ++c)
          acc[r][c] = __builtin_amdgcn_mfma_f32_16x16x32_bf16(af[r], bfr[c],
                                                              acc[r][c], 0, 0, 0);
    }
  }

#pragma unroll
  for (int r = 0; r < MF; ++r) {
    const int row = m0 + wm * (MF * 16) + r * 16 + hi * 4;
#pragma unroll
    for (int c = 0; c < 4; ++c) {
      const int col = n0 + wn * 64 + c * 16 + lrow;
      const float bb = (blockIdx.z == 0) ? bias[col] : 0.f;
#pragma unroll
      for (int j = 0; j < 4; ++j) {
        float v = acc[r][c][j] + bb;
        if (RELU) v = fmaxf(v, 0.f);
        Cz[(size_t)(row + j) * N + col] = (OutT)v;
      }
    }
  }
}

// ---------------------------------------------------------------------------
// Flash attention — R25-verified exactly (QBLK=128 x KVBLK=128, 8 waves,
// DOUBLE-BUFFERED issue-early staging, exp2+defer-max softmax, XCD-clustered
// grid). R26's single-buffer variant regressed (occupancy is wave-count
// capped, not LDS-capped) — reverted to this dbuf version.
// ---------------------------------------------------------------------------
__global__ __launch_bounds__(512) void k_attn(
    const __bf16* __restrict__ qkv, const __bf16* __restrict__ vT,
    const float* __restrict__ mask2, __bf16* __restrict__ out) {
  const int nwg = gridDim.x * gridDim.y * gridDim.z;          // 512
  const int flat = (blockIdx.z * gridDim.y + blockIdx.y) * gridDim.x + blockIdx.x;
  const int cpx = nwg >> 3;                                   // 64
  const int swzb = (flat & 7) * cpx + (flat >> 3);
  const int qb = swzb & (gridDim.x - 1);
  const int h = (swzb >> 4) & 15;
  const int b = swzb >> 8;
  const int tid = threadIdx.x, lane = tid & 63, wv = tid >> 6;
  const int lrow = lane & 15, hi = lane >> 4;

  __shared__ __bf16 sK[2][128 * 64];
  __shared__ __bf16 sV0[2][64 * 64];
  __shared__ __bf16 sV1[2][64 * 64];

  const size_t base = (size_t)b * SEQ * 3072;
  const __bf16* Qb = qkv + base + h * 64;
  const __bf16* Kb = qkv + base + 1024 + h * 64;
  const __bf16* vTb = vT + ((size_t)b * 1024 + h * 64) * SEQ;
  const float* maskb = mask2 + (size_t)b * SEQ;

  const int q0 = qb * 128 + wv * 16;
  const bf16x8 qf0 = *(const bf16x8*)&Qb[(size_t)(q0 + lrow) * 3072 + hi * 8];
  const bf16x8 qf1 = *(const bf16x8*)&Qb[(size_t)(q0 + lrow) * 3072 + 32 + hi * 8];

  float m_r = -3e38f, l_r = 0.f;
  f32x4 o[4];
#pragma unroll
  for (int d = 0; d < 4; ++d) o[d] = f32x4{0.f, 0.f, 0.f, 0.f};

  const int srow = lane >> 3;
  const int scolE = ((lane & 7) ^ srow) * 8;
  const int swz = (lrow & 7) << 4;

  auto stage = [&](int t) {
    const int k0s = t * 128;
    __bf16* dK = sK[t & 1];
    __bf16* dV0 = sV0[t & 1];
    __bf16* dV1 = sV1[t & 1];
#pragma unroll
    for (int r = 0; r < 2; ++r) {
      const int rb = wv + r * 8;
      const int row = rb * 8 + srow;
      gload_lds16(Kb + (size_t)(k0s + row) * 3072 + scolE, &dK[rb * 512]);
    }
    const int vrow = wv * 8 + srow;
    gload_lds16(vTb + (size_t)vrow * SEQ + k0s + scolE, &dV0[wv * 512]);
    gload_lds16(vTb + (size_t)vrow * SEQ + k0s + 64 + scolE, &dV1[wv * 512]);
  };

  stage(0);
  const int NT = SEQ / 128;
  for (int t = 0; t < NT; ++t) {
    __syncthreads();
    if (t + 1 < NT) stage(t + 1);
    const __bf16* cK = sK[t & 1];
    const __bf16* cV0 = sV0[t & 1];
    const __bf16* cV1 = sV1[t & 1];
    const int k0 = t * 128;

    f32x4 st[8];
#pragma unroll
    for (int t4 = 0; t4 < 8; ++t4) {
      const char* rp = (const char*)cK + (t4 * 16 + lrow) * 128;
      const bf16x8 ka = *(const bf16x8*)(rp + ((hi * 16) ^ swz));
      const bf16x8 kb = *(const bf16x8*)(rp + ((64 + hi * 16) ^ swz));
      f32x4 a = f32x4{0.f, 0.f, 0.f, 0.f};
      a = __builtin_amdgcn_mfma_f32_16x16x32_bf16(ka, qf0, a, 0, 0, 0);
      a = __builtin_amdgcn_mfma_f32_16x16x32_bf16(kb, qf1, a, 0, 0, 0);
      st[t4] = a;
    }

    float pm = -3e38f;
#pragma unroll
    for (int t4 = 0; t4 < 8; ++t4) {
      const f32x4 mk = *(const f32x4*)&maskb[k0 + t4 * 16 + hi * 4];
#pragma unroll
      for (int j = 0; j < 4; ++j) {
        st[t4][j] = st[t4][j] * 0.18033688f + mk[j];
        pm = fmaxf(pm, st[t4][j]);
      }
    }
    pm = fmaxf(pm, __shfl_xor(pm, 16));
    pm = fmaxf(pm, __shfl_xor(pm, 32));

    if (__any(pm > m_r + 11.5f)) {
      const float mn = fmaxf(m_r, pm);
      const float so = __builtin_amdgcn_exp2f(m_r - mn);
      m_r = mn;
      l_r *= so;
      float so_o[4];
#pragma unroll
      for (int jj = 0; jj < 4; ++jj) so_o[jj] = __shfl(so, hi * 4 + jj);
#pragma unroll
      for (int d = 0; d < 4; ++d)
#pragma unroll
        for (int jj = 0; jj < 4; ++jj) o[d][jj] *= so_o[jj];
    }

    float rs = 0.f;
#pragma unroll
    for (int t4 = 0; t4 < 8; ++t4)
#pragma unroll
      for (int j = 0; j < 4; ++j) {
        st[t4][j] = __builtin_amdgcn_exp2f(st[t4][j] - m_r);
        rs += st[t4][j];
      }
    rs += __shfl_xor(rs, 16);
    rs += __shfl_xor(rs, 32);
    l_r += rs;

    s16x4 pa[8];
#pragma unroll
    for (int t4 = 0; t4 < 8; ++t4)
#pragma unroll
      for (int j = 0; j < 4; ++j) {
        const __bf16 pb = (__bf16)st[t4][j];
        pa[t4][j] = __builtin_bit_cast(short, pb);
      }

#pragma unroll
    for (int d = 0; d < 4; ++d) {
      const char* rp0 = (const char*)cV0 + (d * 16 + lrow) * 128;
      const char* rp1 = (const char*)cV1 + (d * 16 + lrow) * 128;
#pragma unroll
      for (int t4 = 0; t4 < 4; ++t4) {
        const s16x4 vb0 = *(const s16x4*)(rp0 + ((t4 * 32 + hi * 8) ^ swz));
        o[d] = __builtin_amdgcn_mfma_f32_16x16x16bf16_1k(pa[t4], vb0, o[d], 0, 0, 0);
        const s16x4 vb1 = *(const s16x4*)(rp1 + ((t4 * 32 + hi * 8) ^ swz));
        o[d] = __builtin_amdgcn_mfma_f32_16x16x16bf16_1k(pa[4 + t4], vb1, o[d], 0, 0, 0);
      }
    }
  }

  __syncthreads();
  float linv[4];
#pragma unroll
  for (int jj = 0; jj < 4; ++jj) linv[jj] = 1.0f / __shfl(l_r, hi * 4 + jj);
#pragma unroll
  for (int d = 0; d < 4; ++d)
#pragma unroll
    for (int jj = 0; jj < 4; ++jj)
      out[((size_t)b * SEQ + q0 + hi * 4 + jj) * DMODEL + h * 64 + d * 16 + lrow] =
          (__bf16)(o[d][jj] * linv[jj]);
}

// ---------------------------------------------------------------------------
// out = LayerNorm(x + y [+ y2]) * g + beta. Inputs dtype-templated (f32 or
// bf16); y/y2 nullable; f32 out (of) and bf16 out (ob) each optional.
// ---------------------------------------------------------------------------
template <typename TX, typename TY, typename TY2>
__global__ __launch_bounds__(256) void k_add_ln(
    const TX* __restrict__ x, const TY* __restrict__ y,
    const TY2* __restrict__ y2, const float* __restrict__ g,
    const float* __restrict__ be, float* __restrict__ of,
    __bf16* __restrict__ ob) {
  const int row = blockIdx.x, tid = threadIdx.x;
  const size_t idx = (size_t)row * 256 + tid;
  const float4 a = load4(x, idx);
  float4 b = {0.f, 0.f, 0.f, 0.f};
  if (y) b = load4(y, idx);
  float4 c = {0.f, 0.f, 0.f, 0.f};
  if (y2) c = load4(y2, idx);
  const float v0 = a.x + b.x + c.x, v1 = a.y + b.y + c.y;
  const float v2 = a.z + b.z + c.z, v3 = a.w + b.w + c.w;
  float s = v0 + v1 + v2 + v3;
  float s2 = v0 * v0 + v1 * v1 + v2 * v2 + v3 * v3;
#pragma unroll
  for (int off = 32; off > 0; off >>= 1) {
    s += __shfl_xor(s, off);
    s2 += __shfl_xor(s2, off);
  }
  __shared__ float red[2][4];
  const int wv = tid >> 6, lane = tid & 63;
  if (lane == 0) { red[0][wv] = s; red[1][wv] = s2; }
  __syncthreads();
  s = red[0][0] + red[0][1] + red[0][2] + red[0][3];
  s2 = red[1][0] + red[1][1] + red[1][2] + red[1][3];
  const float mean = s * (1.0f / 1024.0f);
  const float var = s2 * (1.0f / 1024.0f) - mean * mean;
  const float rstd = rsqrtf(var + 1e-5f);
  const float4 gg = ((const float4*)g)[tid];
  const float4 bt = ((const float4*)be)[tid];
  float4 r;
  r.x = (v0 - mean) * rstd * gg.x + bt.x;
  r.y = (v1 - mean) * rstd * gg.y + bt.y;
  r.z = (v2 - mean) * rstd * gg.z + bt.z;
  r.w = (v3 - mean) * rstd * gg.w + bt.w;
  if (of) ((float4*)(of + (size_t)row * 1024))[tid] = r;
  if (ob) {
    bf16x4 rb;
    rb[0] = (__bf16)r.x; rb[1] = (__bf16)r.y; rb[2] = (__bf16)r.z; rb[3] = (__bf16)r.w;
    *(bf16x4*)(ob + (size_t)row * 1024 + tid * 4) = rb;
  }
}

// ---------------------------------------------------------------------------
extern "C" void kernel_launch(void* const* d_in, const int* in_sizes, int n_in,
                              void* d_out, int out_size, void* d_ws, size_t ws_size,
                              hipStream_t stream) {
  const float* x = (const float*)d_in[0];
  const float* src_mask = (const float*)d_in[1];
  const float* w_q = (const float*)d_in[2];
  const float* b_q = (const float*)d_in[3];
  const float* w_k = (const float*)d_in[4];
  const float* b_k = (const float*)d_in[5];
  const float* w_v = (const float*)d_in[6];
  const float* b_v = (const float*)d_in[7];
  const float* w_o = (const float*)d_in[8];
  const float* b_o = (const float*)d_in[9];
  const float* w_ff1 = (const float*)d_in[10];
  const float* b_ff1 = (const float*)d_in[11];
  const float* w_ff2 = (const float*)d_in[12];
  const float* b_ff2 = (const float*)d_in[13];
  const float* ln1_g = (const float*)d_in[14];
  const float* ln1_b = (const float*)d_in[15];
  const float* ln2_g = (const float*)d_in[16];
  const float* ln2_b = (const float*)d_in[17];

  char* ws = (char*)d_ws;
  constexpr size_t O_WQKVT = 0;
  constexpr size_t O_WOT = O_WQKVT + 3072ull * 1024 * 2;
  constexpr size_t O_WFF1T = O_WOT + 1024ull * 1024 * 2;
  constexpr size_t O_WFF2T = O_WFF1T + 4096ull * 1024 * 2;
  constexpr size_t O_BQKV = O_WFF2T + 4096ull * 1024 * 2;
  constexpr size_t O_XBF = O_BQKV + 3072ull * 4;
  constexpr size_t O_QKV = O_XBF + 4096ull * 1024 * 2;
  constexpr size_t O_ATTN = O_QKV + 4096ull * 3072 * 2;
  constexpr size_t O_PROJ = O_ATTN + 4096ull * 1024 * 2;   // region reused 3x
  constexpr size_t O_H1F = O_PROJ + 4096ull * 1024 * 4;
  constexpr size_t O_H1B = O_H1F + 4096ull * 1024 * 4;
  constexpr size_t O_MASK2 = O_H1B + 4096ull * 1024 * 2;   // 16KB
  constexpr size_t O_VT = O_PROJ;    // vT (8MB): dead once proj written
  constexpr size_t O_FF = O_QKV;     // ffb 32MB spans QKV+ATTN
  constexpr size_t O_PROJB = O_PROJ; // proj bf16 8MB (after vT dead)
  constexpr size_t O_FF2A = O_PROJ;  // ff2a bf16 8MB (projb dead after ln1)
  constexpr size_t O_FF2B = 0;       // ff2b bf16 8MB over dead wqkvT+woT

  __bf16* wqkvT = (__bf16*)(ws + O_WQKVT);
  __bf16* woT = (__bf16*)(ws + O_WOT);
  __bf16* wff1T = (__bf16*)(ws + O_WFF1T);
  __bf16* wff2T = (__bf16*)(ws + O_WFF2T);
  float* bqkv = (float*)(ws + O_BQKV);
  __bf16* xbf = (__bf16*)(ws + O_XBF);
  __bf16* qkvb = (__bf16*)(ws + O_QKV);
  __bf16* attnb = (__bf16*)(ws + O_ATTN);
  __bf16* projb = (__bf16*)(ws + O_PROJB);
  __bf16* h1b = (__bf16*)(ws + O_H1B);
  float* mask2 = (float*)(ws + O_MASK2);
  __bf16* vT = (__bf16*)(ws + O_VT);
  __bf16* ffb = (__bf16*)(ws + O_FF);
  __bf16* ff2a = (__bf16*)(ws + O_FF2A);
  __bf16* ff2b = (__bf16*)(ws + O_FF2B);

  // fused prep: all transposes + concat + mask scale + x->bf16, ONE dispatch
  k_prep<<<16412, 256, 0, stream>>>(w_q, w_k, w_v, w_o, w_ff1, w_ff2,
                                    wqkvT, woT, wff1T, wff2T,
                                    b_q, b_k, b_v, bqkv,
                                    src_mask, mask2, x, xbf);

  // fused QKV projection (256^2 counted-vmcnt pipeline)
  k_gemm256<false, __bf16><<<dim3(12, 16), 512, 0, stream>>>(xbf, wqkvT, bqkv, qkvb,
                                                             MTOT, 3072, 1024);
  // V transpose (vectorized 64x64 tiles)
  k_transpose_v<<<dim3(32, 16, 2), 256, 0, stream>>>(qkvb, vT);
  // attention (R25-verified dbuf, QBLK=128 x KVBLK=128)
  k_attn<<<dim3(SEQ / 128, NHEAD, BATCH), 512, 0, stream>>>(qkvb, vT, mask2, attnb);
  // output projection -> bf16
  k_gemm<2, false, __bf16><<<dim3(8, 64, 1), 256, 0, stream>>>(
      attnb, woT, b_o, projb, nullptr, MTOT, 1024, 1024, 1024);
  // ln1: h1 = LN(xbf + proj) -> bf16 only (xbf instead of f32 x: -8MB reads)
  k_add_ln<__bf16, __bf16, float><<<4096, 256, 0, stream>>>(
      xbf, projb, (const float*)nullptr, ln1_g, ln1_b, nullptr, h1b);
  // ff1 + relu (256^2 counted-vmcnt pipeline)
  k_gemm256<true, __bf16><<<dim3(16, 16), 512, 0, stream>>>(h1b, wff1T, b_ff1, ffb,
                                                            MTOT, DFF, 1024);
  // ff2 split-K x2 in ONE dispatch, bf16 partials
  k_gemm<2, false, __bf16><<<dim3(8, 64, 2), 256, 0, stream>>>(
      ffb, wff2T, b_ff2, ff2a, ff2b, MTOT, 1024, DFF, 2048);
  // ln2 -> d_out: ff2a + h1b + ff2b (all bf16 in, f32 out)
  k_add_ln<__bf16, __bf16, __bf16><<<4096, 256, 0, stream>>>(
      ff2a, h1b, ff2b, ln2_g, ln2_b, (float*)d_out, nullptr);
}